// Round 9
// baseline (24174.136 us; speedup 1.0000x reference)
//
#include <hip/hip_runtime.h>

// ---------------------------------------------------------------------------
// ROUND 9: fp32 everywhere, FP32 OUTPUT (the round-4..8 bug: output buffer is
// float32 per the reference's output dtype; bf16-u16 writes scrambled it).
// Tiled GEMM + wave-per-query attention, chunked to fit ws_size.
// ---------------------------------------------------------------------------

#define Bc 128
#define Tc 256
#define Ec 384
#define Hc 6
#define HSc 64
#define Lc 6
#define Vc 78
#define FFc 1536
#define Mc (Bc * Tc)  // 32768 tokens

__global__ __launch_bounds__(256) void poison_kernel(
    float* __restrict__ out, int n, float val) {
    int i = blockIdx.x * 256 + threadIdx.x;
    if (i < n) out[i] = val;
}

// x[bt,e] = tok_emb[ctx[bt],e] + pos_emb[t,e]
__global__ __launch_bounds__(256) void embed_kernel(
    const int* __restrict__ ctx, const float* __restrict__ tok,
    const float* __restrict__ pos, float* __restrict__ x) {
    int i = blockIdx.x * 256 + threadIdx.x;
    if (i >= Mc * Ec) return;
    int e = i % Ec, bt = i / Ec, t = bt % Tc;
    x[i] = tok[ctx[bt] * Ec + e] + pos[t * Ec + e];
}

// layernorm fp32->fp32: one wave per row of E=384
__global__ __launch_bounds__(256) void ln_kernel(
    const float* __restrict__ X, float* __restrict__ Y,
    const float* __restrict__ g, const float* __restrict__ b, int nrows) {
    int row = blockIdx.x * 4 + (threadIdx.x >> 6);
    int lane = threadIdx.x & 63;
    if (row >= nrows) return;
    const float* xr = X + (size_t)row * Ec;
    float v[6];
    float s = 0.f;
#pragma unroll
    for (int i = 0; i < 6; ++i) { v[i] = xr[lane + 64 * i]; s += v[i]; }
#pragma unroll
    for (int off = 32; off >= 1; off >>= 1) s += __shfl_xor(s, off, 64);
    float mean = s * (1.0f / Ec);
    float s2 = 0.f;
#pragma unroll
    for (int i = 0; i < 6; ++i) { float d = v[i] - mean; s2 += d * d; }
#pragma unroll
    for (int off = 32; off >= 1; off >>= 1) s2 += __shfl_xor(s2, off, 64);
    float rstd = rsqrtf(s2 * (1.0f / Ec) + 1e-5f);
    float* yr = Y + (size_t)row * Ec;
#pragma unroll
    for (int i = 0; i < 6; ++i) {
        int e = lane + 64 * i;
        yr[e] = (v[i] - mean) * rstd * g[e] + b[e];
    }
}

// tiled GEMM: C[m, ldC] (+R) = A[M,K] @ W[K,N] [+bias]; all fp32.
// M mult of 64, K mult of 16. R==C allowed (same-element in-place residual).
template <bool RELU, bool RESID>
__global__ __launch_bounds__(256) void gemm_kernel(
    const float* __restrict__ A, const float* __restrict__ W,
    const float* __restrict__ bias, const float* R, float* C,
    int M, int N, int K, int ldC) {
    __shared__ float As[64][17];
    __shared__ float Bs[16][68];
    int tid = threadIdx.x;
    int m0 = blockIdx.y * 64;
    int n0 = blockIdx.x * 64;
    int ty = tid >> 4, tx = tid & 15;
    int arow = tid >> 2, acol = (tid & 3) * 4;
    int wrow = tid >> 4, wcol = (tid & 15) * 4;
    bool nvec = (N & 63) == 0;
    float acc[4][4];
#pragma unroll
    for (int i = 0; i < 4; ++i)
#pragma unroll
        for (int j = 0; j < 4; ++j) acc[i][j] = 0.f;

    for (int k0 = 0; k0 < K; k0 += 16) {
        float4 av = *reinterpret_cast<const float4*>(
            &A[(size_t)(m0 + arow) * K + k0 + acol]);
        As[arow][acol + 0] = av.x;
        As[arow][acol + 1] = av.y;
        As[arow][acol + 2] = av.z;
        As[arow][acol + 3] = av.w;
        int gn = n0 + wcol;
        if (nvec) {
            float4 wv = *reinterpret_cast<const float4*>(
                &W[(size_t)(k0 + wrow) * N + gn]);
            Bs[wrow][wcol + 0] = wv.x;
            Bs[wrow][wcol + 1] = wv.y;
            Bs[wrow][wcol + 2] = wv.z;
            Bs[wrow][wcol + 3] = wv.w;
        } else {
#pragma unroll
            for (int j = 0; j < 4; ++j)
                Bs[wrow][wcol + j] =
                    (gn + j < N) ? W[(size_t)(k0 + wrow) * N + gn + j] : 0.f;
        }
        __syncthreads();
#pragma unroll
        for (int kk = 0; kk < 16; ++kk) {
            float a[4], bb[4];
#pragma unroll
            for (int i = 0; i < 4; ++i) a[i] = As[ty * 4 + i][kk];
#pragma unroll
            for (int j = 0; j < 4; ++j) bb[j] = Bs[kk][tx * 4 + j];
#pragma unroll
            for (int i = 0; i < 4; ++i)
#pragma unroll
                for (int j = 0; j < 4; ++j) acc[i][j] += a[i] * bb[j];
        }
        __syncthreads();
    }

#pragma unroll
    for (int i = 0; i < 4; ++i) {
        int m = m0 + ty * 4 + i;
#pragma unroll
        for (int j = 0; j < 4; ++j) {
            int n = n0 + tx * 4 + j;
            if (n < N) {
                float v = acc[i][j];
                if (bias) v += bias[n];
                if (RESID) v += R[(size_t)m * ldC + n];
                if (RELU) v = fmaxf(v, 0.f);
                C[(size_t)m * ldC + n] = v;
            }
        }
    }
}

// attention: one WAVE per (b,h,t). qkv [bcnt*T,1152] fp32; o [bcnt*T,E] fp32.
// grid: (Tc/4, Hc, bcnt), block 256.
__global__ __launch_bounds__(256) void attn_kernel(
    const float* __restrict__ qkv, float* __restrict__ o) {
    int w = threadIdx.x >> 6;
    int lane = threadIdx.x & 63;
    int t = blockIdx.x * 4 + w;
    int h = blockIdx.y, b = blockIdx.z;
    __shared__ float qs[4][64];
    __shared__ float sc[4][256];
    const float* base = qkv + (size_t)b * Tc * 1152 + h * 192;

    qs[w][lane] = base[(size_t)t * 1152 + lane];
    __syncthreads();

    const float NEG = -3.0e38f;
    float s0[4];
    float m = NEG;
#pragma unroll
    for (int i = 0; i < 4; ++i) {
        int s = 64 * i + lane;
        const float* kp = base + (size_t)s * 1152 + 64;
        float dot = 0.f;
#pragma unroll
        for (int d = 0; d < 64; d += 4) {
            float4 kv = *reinterpret_cast<const float4*>(kp + d);
            dot += qs[w][d + 0] * kv.x + qs[w][d + 1] * kv.y +
                   qs[w][d + 2] * kv.z + qs[w][d + 3] * kv.w;
        }
        s0[i] = (s <= t) ? dot * 0.125f : NEG;  // HS^-0.5 = 1/8
        m = fmaxf(m, s0[i]);
    }
#pragma unroll
    for (int off = 32; off >= 1; off >>= 1) m = fmaxf(m, __shfl_xor(m, off, 64));

    float sum = 0.f;
    float p[4];
#pragma unroll
    for (int i = 0; i < 4; ++i) {
        int s = 64 * i + lane;
        p[i] = (s <= t) ? expf(s0[i] - m) : 0.f;
        sum += p[i];
    }
#pragma unroll
    for (int off = 32; off >= 1; off >>= 1) sum += __shfl_xor(sum, off, 64);
    float inv = 1.0f / sum;
#pragma unroll
    for (int i = 0; i < 4; ++i) sc[w][64 * i + lane] = p[i] * inv;
    __syncthreads();

    float acc = 0.f;
    for (int s = 0; s <= t; ++s)
        acc += sc[w][s] * base[(size_t)s * 1152 + 128 + lane];
    o[((size_t)(b * Tc + t)) * Ec + h * 64 + lane] = acc;
}

#define GRD(n) dim3(((n) + 255) / 256)

extern "C" void kernel_launch(void* const* d_in, const int* in_sizes, int n_in,
                              void* d_out, int out_size, void* d_ws, size_t ws_size,
                              hipStream_t stream) {
    const int* ctx = (const int*)d_in[0];
    const float* tok = (const float*)d_in[1];
    const float* pos = (const float*)d_in[2];
    const float* ln1g = (const float*)d_in[3];
    const float* ln1b = (const float*)d_in[4];
    const float* wqkv = (const float*)d_in[5];
    const float* wproj = (const float*)d_in[6];
    const float* bproj = (const float*)d_in[7];
    const float* ln2g = (const float*)d_in[8];
    const float* ln2b = (const float*)d_in[9];
    const float* w1 = (const float*)d_in[10];
    const float* b1 = (const float*)d_in[11];
    const float* w2 = (const float*)d_in[12];
    const float* b2 = (const float*)d_in[13];
    const float* lnfg = (const float*)d_in[14];
    const float* lnfb = (const float*)d_in[15];
    const float* whead = (const float*)d_in[16];
    const float* bhead = (const float*)d_in[17];
    float* out = (float*)d_out;

    // workspace: x fp32 [M,E] + per-chunk fp32 {xn, o, qkv, ff}
    const size_t xbytes = (size_t)Mc * Ec * 4;  // 50.3 MB
    const size_t per_b = (size_t)Tc * (Ec + Ec + 1152 + FFc) * 4;  // 3,538,944 B
    if (ws_size < xbytes + per_b) {
        poison_kernel<<<GRD(out_size), 256, 0, stream>>>(out, out_size, 200.0f);
        return;
    }
    int CB = (int)((ws_size - xbytes) / per_b);
    if (CB > Bc) CB = Bc;

    float* x = (float*)d_ws;
    float* xn_c = x + (size_t)Mc * Ec;
    float* o_c = xn_c + (size_t)CB * Tc * Ec;
    float* qkv_c = o_c + (size_t)CB * Tc * Ec;
    float* ff_c = qkv_c + (size_t)CB * Tc * 1152;

    embed_kernel<<<GRD(Mc * Ec), 256, 0, stream>>>(ctx, tok, pos, x);

    for (int l = 0; l < Lc; ++l) {
        const float* wq_l = wqkv + (size_t)l * Hc * Ec * 192;
        const float* wp_l = wproj + (size_t)l * Ec * Ec;
        const float* w1_l = w1 + (size_t)l * Ec * FFc;
        const float* w2_l = w2 + (size_t)l * FFc * Ec;
        for (int b0 = 0; b0 < Bc; b0 += CB) {
            int bcnt = (Bc - b0 < CB) ? (Bc - b0) : CB;
            int rows = bcnt * Tc;
            float* xc = x + (size_t)b0 * Tc * Ec;
            ln_kernel<<<rows / 4, 256, 0, stream>>>(
                xc, xn_c, ln1g + l * Ec, ln1b + l * Ec, rows);
            for (int h = 0; h < Hc; ++h)
                gemm_kernel<false, false><<<dim3(3, rows / 64), 256, 0, stream>>>(
                    xn_c, wq_l + (size_t)h * Ec * 192, nullptr, nullptr,
                    qkv_c + h * 192, rows, 192, Ec, 1152);
            attn_kernel<<<dim3(Tc / 4, Hc, bcnt), 256, 0, stream>>>(qkv_c, o_c);
            gemm_kernel<false, true><<<dim3(Ec / 64, rows / 64), 256, 0, stream>>>(
                o_c, wp_l, bproj + l * Ec, xc, xc, rows, Ec, Ec, Ec);
            ln_kernel<<<rows / 4, 256, 0, stream>>>(
                xc, xn_c, ln2g + l * Ec, ln2b + l * Ec, rows);
            gemm_kernel<true, false><<<dim3(FFc / 64, rows / 64), 256, 0, stream>>>(
                xn_c, w1_l, b1 + l * FFc, nullptr, ff_c, rows, FFc, Ec, FFc);
            gemm_kernel<false, true><<<dim3(Ec / 64, rows / 64), 256, 0, stream>>>(
                ff_c, w2_l, b2 + l * Ec, xc, xc, rows, Ec, FFc, Ec);
        }
    }
    for (int b0 = 0; b0 < Bc; b0 += CB) {
        int bcnt = (Bc - b0 < CB) ? (Bc - b0) : CB;
        int rows = bcnt * Tc;
        float* xc = x + (size_t)b0 * Tc * Ec;
        ln_kernel<<<rows / 4, 256, 0, stream>>>(xc, xn_c, lnfg, lnfb, rows);
        gemm_kernel<false, false><<<dim3(2, rows / 64), 256, 0, stream>>>(
            xn_c, whead, bhead, nullptr, out + (size_t)b0 * Tc * Vc,
            rows, Vc, Ec, Vc);
    }
}

// Round 10
// 4863.832 us; speedup vs baseline: 4.9702x; 4.9702x over previous
//
#include <hip/hip_runtime.h>

// ---------------------------------------------------------------------------
// ROUND 10: bf16-MFMA GEMMs + LDS flash attention. fp32 residual/output.
// B=128 T=256 E=384 H=6 HS=64 L=6 V=78 FF=1536. Output fp32 (verified r9).
// ---------------------------------------------------------------------------

#define Bc 128
#define Tc 256
#define Ec 384
#define Hc 6
#define HSc 64
#define Lc 6
#define Vc 78
#define FFc 1536
#define Mc (Bc * Tc)  // 32768 tokens

typedef unsigned short u16;
using bf16x8 = __attribute__((ext_vector_type(8))) short;
using f32x4 = __attribute__((ext_vector_type(4))) float;

__device__ __forceinline__ float b2f(u16 u) {
    union { float f; unsigned int i; } x;
    x.i = ((unsigned int)u) << 16;
    return x.f;
}
__device__ __forceinline__ u16 f2b(float f) {
    union { float f; unsigned int u; } x;
    x.f = f;
    unsigned int r = x.u + 0x7fffu + ((x.u >> 16) & 1u);  // RNE
    return (u16)(r >> 16);
}

__global__ __launch_bounds__(256) void poison_kernel(
    float* __restrict__ out, int n, float val) {
    int i = blockIdx.x * 256 + threadIdx.x;
    if (i < n) out[i] = val;
}

// --- weight pre-transpose to bf16 [N][K] ------------------------------------
__global__ __launch_bounds__(256) void trans_qkv_kernel(
    const float* __restrict__ in, u16* __restrict__ out) {
    int i = blockIdx.x * 256 + threadIdx.x;  // < L*H*E*192
    if (i >= Lc * Hc * Ec * 192) return;
    int f = i % 192;
    int r = i / 192;
    int e = r % Ec; r /= Ec;
    int h = r % Hc;
    int l = r / Hc;
    out[((size_t)l * 1152 + h * 192 + f) * Ec + e] = f2b(in[i]);
}
__global__ __launch_bounds__(256) void trans_w_kernel(
    const float* __restrict__ in, u16* __restrict__ out, int K, int N) {
    int i = blockIdx.x * 256 + threadIdx.x;  // < L*K*N
    if (i >= Lc * K * N) return;
    int n = i % N;
    int r = i / N;
    int k = r % K;
    int l = r / K;
    out[((size_t)l * N + n) * K + k] = f2b(in[i]);
}

// --- x[bt,e] = tok_emb[ctx[bt],e] + pos_emb[t,e]  (fp32) --------------------
__global__ __launch_bounds__(256) void embed_kernel(
    const int* __restrict__ ctx, const float* __restrict__ tok,
    const float* __restrict__ pos, float* __restrict__ x) {
    int i = blockIdx.x * 256 + threadIdx.x;
    if (i >= Mc * Ec) return;
    int e = i % Ec, bt = i / Ec, t = bt % Tc;
    x[i] = tok[ctx[bt] * Ec + e] + pos[t * Ec + e];
}

// --- layernorm fp32 in -> bf16 out: one wave per row ------------------------
__global__ __launch_bounds__(256) void ln_kernel(
    const float* __restrict__ X, u16* __restrict__ Y,
    const float* __restrict__ g, const float* __restrict__ b, int nrows) {
    int row = blockIdx.x * 4 + (threadIdx.x >> 6);
    int lane = threadIdx.x & 63;
    if (row >= nrows) return;
    const float* xr = X + (size_t)row * Ec;
    float v[6];
    float s = 0.f;
#pragma unroll
    for (int i = 0; i < 6; ++i) { v[i] = xr[lane + 64 * i]; s += v[i]; }
#pragma unroll
    for (int off = 32; off >= 1; off >>= 1) s += __shfl_xor(s, off, 64);
    float mean = s * (1.0f / Ec);
    float s2 = 0.f;
#pragma unroll
    for (int i = 0; i < 6; ++i) { float d = v[i] - mean; s2 += d * d; }
#pragma unroll
    for (int off = 32; off >= 1; off >>= 1) s2 += __shfl_xor(s2, off, 64);
    float rstd = rsqrtf(s2 * (1.0f / Ec) + 1e-5f);
    u16* yr = Y + (size_t)row * Ec;
#pragma unroll
    for (int i = 0; i < 6; ++i) {
        int e = lane + 64 * i;
        yr[e] = f2b((v[i] - mean) * rstd * g[e] + b[e]);
    }
}

// --- MFMA GEMM: C[*, ldC] = A[M,K](bf16) @ Wt[N,K]^T(bf16) [+bias][+R] ------
// 128x128 tile, BK=64, 4 waves (2x2 of 64x64). M=grid.y*128, N=grid.x*128.
// mfma_f32_16x16x32_bf16: A[m=lane&15][k=quad*8+j]; B[k=quad*8+j][n=lane&15];
// C/D[row=quad*4+reg][col=lane&15]  (m89-verified layouts).
template <bool RELU, bool RESID, bool OUTBF16>
__global__ __launch_bounds__(256) void mfma_gemm(
    const u16* __restrict__ A, const u16* __restrict__ Wt,
    const float* __restrict__ bias, const float* R, void* C,
    int N, int K, int ldC) {
    __shared__ u16 As[128][80];  // 80 = 64 + 16B pad (aligned, 2-way banks)
    __shared__ u16 Bs[128][80];
    int tid = threadIdx.x;
    int m0 = blockIdx.y * 128, n0 = blockIdx.x * 128;
    int w = tid >> 6, lane = tid & 63;
    int wm = (w >> 1) * 64, wn = (w & 1) * 64;
    int r16 = lane & 15, quad = lane >> 4;
    int sr = tid >> 3;       // staging row 0..31 (4 passes)
    int sk = (tid & 7) * 8;  // staging k-offset (8 bf16 = 16B per load)

    f32x4 acc[4][4] = {};

    for (int k0 = 0; k0 < K; k0 += 64) {
        __syncthreads();
#pragma unroll
        for (int j = 0; j < 4; ++j) {
            int r = sr + 32 * j;
            *reinterpret_cast<uint4*>(&As[r][sk]) =
                *reinterpret_cast<const uint4*>(&A[(size_t)(m0 + r) * K + k0 + sk]);
            *reinterpret_cast<uint4*>(&Bs[r][sk]) =
                *reinterpret_cast<const uint4*>(&Wt[(size_t)(n0 + r) * K + k0 + sk]);
        }
        __syncthreads();
#pragma unroll
        for (int kk = 0; kk < 2; ++kk) {
            bf16x8 af[4], bf[4];
#pragma unroll
            for (int i = 0; i < 4; ++i) {
                af[i] = *reinterpret_cast<const bf16x8*>(
                    &As[wm + i * 16 + r16][kk * 32 + quad * 8]);
                bf[i] = *reinterpret_cast<const bf16x8*>(
                    &Bs[wn + i * 16 + r16][kk * 32 + quad * 8]);
            }
#pragma unroll
            for (int mi = 0; mi < 4; ++mi)
#pragma unroll
                for (int ni = 0; ni < 4; ++ni)
                    acc[mi][ni] = __builtin_amdgcn_mfma_f32_16x16x32_bf16(
                        af[mi], bf[ni], acc[mi][ni], 0, 0, 0);
        }
    }

#pragma unroll
    for (int mi = 0; mi < 4; ++mi)
#pragma unroll
        for (int ni = 0; ni < 4; ++ni) {
            int gn = n0 + wn + ni * 16 + r16;
            float bv = bias ? bias[gn] : 0.f;
#pragma unroll
            for (int reg = 0; reg < 4; ++reg) {
                int gm = m0 + wm + mi * 16 + quad * 4 + reg;
                float v = acc[mi][ni][reg] + bv;
                if (RESID) v += R[(size_t)gm * ldC + gn];
                if (RELU) v = fmaxf(v, 0.f);
                if (OUTBF16)
                    ((u16*)C)[(size_t)gm * ldC + gn] = f2b(v);
                else
                    ((float*)C)[(size_t)gm * ldC + gn] = v;
            }
        }
}

// --- flash attention: block = (q-tile 64, h, b); 4 waves x 16 queries -------
// qkv [bcnt*256,1152] bf16 chunk-local; o [bcnt*256,384] bf16 chunk-local.
__global__ __launch_bounds__(256) void attn_kernel(
    const u16* __restrict__ qkv, u16* __restrict__ o) {
    __shared__ float Qs[64][68];
    __shared__ float Ks[64][68];
    __shared__ float Vs[64][68];
    __shared__ u16 Ps[4][16][66];
    int tid = threadIdx.x;
    int tt = blockIdx.x, h = blockIdx.y, b = blockIdx.z;
    int w = tid >> 6, lane = tid & 63;
    int qi = lane & 15, quad = lane >> 4;
    int t0 = tt * 64;
    const u16* base = qkv + (size_t)b * Tc * 1152 + h * 192;

    {   // stage Q tile (64x64) fp32
        int r = tid >> 2, d0 = (tid & 3) * 16;
        const u16* src = base + (size_t)(t0 + r) * 1152 + d0;
        u16 tmp[16];
        *reinterpret_cast<uint4*>(tmp) = *reinterpret_cast<const uint4*>(src);
        *reinterpret_cast<uint4*>(tmp + 8) =
            *reinterpret_cast<const uint4*>(src + 8);
#pragma unroll
        for (int j = 0; j < 16; ++j) Qs[r][d0 + j] = b2f(tmp[j]);
    }

    float m_run = -3.0e38f, l_run = 0.f;
    float o_reg[16];
#pragma unroll
    for (int j = 0; j < 16; ++j) o_reg[j] = 0.f;
    int qg = w * 16 + qi;  // query index within tile

    for (int st = 0; st <= tt; ++st) {
        __syncthreads();
        {   // stage K,V s-tile (64x64 each) fp32
            int r = tid >> 2, d0 = (tid & 3) * 16;
            const u16* ks = base + (size_t)(st * 64 + r) * 1152 + 64 + d0;
            const u16* vs = base + (size_t)(st * 64 + r) * 1152 + 128 + d0;
            u16 tk[16], tv[16];
            *reinterpret_cast<uint4*>(tk) = *reinterpret_cast<const uint4*>(ks);
            *reinterpret_cast<uint4*>(tk + 8) = *reinterpret_cast<const uint4*>(ks + 8);
            *reinterpret_cast<uint4*>(tv) = *reinterpret_cast<const uint4*>(vs);
            *reinterpret_cast<uint4*>(tv + 8) = *reinterpret_cast<const uint4*>(vs + 8);
#pragma unroll
            for (int j = 0; j < 16; ++j) { Ks[r][d0 + j] = b2f(tk[j]); Vs[r][d0 + j] = b2f(tv[j]); }
        }
        __syncthreads();

        // QK^T: lane computes 16 scores (s = quad*16+j) for query qg
        float sc[16];
#pragma unroll
        for (int j = 0; j < 16; ++j) sc[j] = 0.f;
        for (int d8 = 0; d8 < 8; ++d8) {
            float4 q0 = *reinterpret_cast<const float4*>(&Qs[qg][d8 * 8]);
            float4 q1 = *reinterpret_cast<const float4*>(&Qs[qg][d8 * 8 + 4]);
#pragma unroll
            for (int j = 0; j < 16; ++j) {
                int s = quad * 16 + j;
                float4 k0 = *reinterpret_cast<const float4*>(&Ks[s][d8 * 8]);
                float4 k1 = *reinterpret_cast<const float4*>(&Ks[s][d8 * 8 + 4]);
                sc[j] += q0.x * k0.x + q0.y * k0.y + q0.z * k0.z + q0.w * k0.w +
                         q1.x * k1.x + q1.y * k1.y + q1.z * k1.z + q1.w * k1.w;
            }
        }
        float mt = -3.0e38f;
#pragma unroll
        for (int j = 0; j < 16; ++j) {
            int s = quad * 16 + j;
            bool valid = (st < tt) || (s <= qg);
            sc[j] = valid ? sc[j] * 0.125f : -3.0e38f;
            mt = fmaxf(mt, sc[j]);
        }
        mt = fmaxf(mt, __shfl_xor(mt, 16, 64));
        mt = fmaxf(mt, __shfl_xor(mt, 32, 64));
        float m_new = fmaxf(m_run, mt);
        float alpha = __expf(m_run - m_new);
        float lt = 0.f;
#pragma unroll
        for (int j = 0; j < 16; ++j) {
            float p = __expf(sc[j] - m_new);
            lt += p;
            Ps[w][qi][quad * 16 + j] = f2b(p);
        }
        lt += __shfl_xor(lt, 16, 64);
        lt += __shfl_xor(lt, 32, 64);
        l_run = l_run * alpha + lt;
        m_run = m_new;
#pragma unroll
        for (int j = 0; j < 16; ++j) o_reg[j] *= alpha;

        // PV: lane accumulates o[qg][quad*16 .. +16)
        for (int s = 0; s < 64; ++s) {
            float p = b2f(Ps[w][qi][s]);
            const float* vr = &Vs[s][quad * 16];
            float4 v0 = *reinterpret_cast<const float4*>(vr);
            float4 v1 = *reinterpret_cast<const float4*>(vr + 4);
            float4 v2 = *reinterpret_cast<const float4*>(vr + 8);
            float4 v3 = *reinterpret_cast<const float4*>(vr + 12);
            o_reg[0] += p * v0.x;  o_reg[1] += p * v0.y;
            o_reg[2] += p * v0.z;  o_reg[3] += p * v0.w;
            o_reg[4] += p * v1.x;  o_reg[5] += p * v1.y;
            o_reg[6] += p * v1.z;  o_reg[7] += p * v1.w;
            o_reg[8] += p * v2.x;  o_reg[9] += p * v2.y;
            o_reg[10] += p * v2.z; o_reg[11] += p * v2.w;
            o_reg[12] += p * v3.x; o_reg[13] += p * v3.y;
            o_reg[14] += p * v3.z; o_reg[15] += p * v3.w;
        }
    }
    float inv = 1.0f / l_run;
    u16* op = o + ((size_t)b * Tc + t0 + qg) * Ec + h * 64 + quad * 16;
#pragma unroll
    for (int j = 0; j < 16; ++j) op[j] = f2b(o_reg[j] * inv);
}

// --- head: out[m,v] = sum_e xn[m,e]*W[e,v] + bias[v]  (fp32 out) ------------
__global__ __launch_bounds__(256) void head_kernel(
    const u16* __restrict__ xn, const float* __restrict__ W,
    const float* __restrict__ bias, float* __restrict__ out, int rows) {
    int i = blockIdx.x * 256 + threadIdx.x;
    if (i >= rows * Vc) return;
    int m = i / Vc, v = i % Vc;
    const u16* xm = xn + (size_t)m * Ec;
    float acc = 0.f;
    for (int e = 0; e < Ec; ++e) acc += b2f(xm[e]) * W[(size_t)e * Vc + v];
    out[i] = acc + bias[v];
}

#define GRD(n) dim3(((n) + 255) / 256)

extern "C" void kernel_launch(void* const* d_in, const int* in_sizes, int n_in,
                              void* d_out, int out_size, void* d_ws, size_t ws_size,
                              hipStream_t stream) {
    const int* ctx = (const int*)d_in[0];
    const float* tok = (const float*)d_in[1];
    const float* pos = (const float*)d_in[2];
    const float* ln1g = (const float*)d_in[3];
    const float* ln1b = (const float*)d_in[4];
    const float* wqkv = (const float*)d_in[5];
    const float* wproj = (const float*)d_in[6];
    const float* bproj = (const float*)d_in[7];
    const float* ln2g = (const float*)d_in[8];
    const float* ln2b = (const float*)d_in[9];
    const float* w1 = (const float*)d_in[10];
    const float* b1 = (const float*)d_in[11];
    const float* w2 = (const float*)d_in[12];
    const float* b2 = (const float*)d_in[13];
    const float* lnfg = (const float*)d_in[14];
    const float* lnfb = (const float*)d_in[15];
    const float* whead = (const float*)d_in[16];
    const float* bhead = (const float*)d_in[17];
    float* out = (float*)d_out;

    // ---- workspace layout --------------------------------------------------
    // x fp32 [M,E] | wT bf16 (qkv 1152x384, proj 384x384, w1 1536x384,
    // w2 384x1536 per layer) | chunk scratch bf16 {xn, qkv, o, ff}
    char* ws = (char*)d_ws;
    float* x = (float*)ws;
    size_t off = (size_t)Mc * Ec * 4;                      // 50.3 MB
    u16* wqkvT = (u16*)(ws + off); off += (size_t)Lc * 1152 * 384 * 2;
    u16* wprojT = (u16*)(ws + off); off += (size_t)Lc * 384 * 384 * 2;
    u16* w1T = (u16*)(ws + off); off += (size_t)Lc * 1536 * 384 * 2;
    u16* w2T = (u16*)(ws + off); off += (size_t)Lc * 384 * 1536 * 2;
    const size_t per_b = (size_t)Tc * (Ec + 1152 + Ec + FFc) * 2;  // 1.77 MB
    if (ws_size < off + per_b) {
        poison_kernel<<<GRD(out_size), 256, 0, stream>>>(out, out_size, 200.0f);
        return;
    }
    int CB = (int)((ws_size - off) / per_b);
    if (CB > Bc) CB = Bc;
    u16* xn_c = (u16*)(ws + off);
    u16* qkv_c = xn_c + (size_t)CB * Tc * Ec;
    u16* o_c = qkv_c + (size_t)CB * Tc * 1152;
    u16* ff_c = o_c + (size_t)CB * Tc * Ec;

    // ---- weight transposes (bf16) -----------------------------------------
    trans_qkv_kernel<<<GRD(Lc * Hc * Ec * 192), 256, 0, stream>>>(wqkv, wqkvT);
    trans_w_kernel<<<GRD(Lc * Ec * Ec), 256, 0, stream>>>(wproj, wprojT, Ec, Ec);
    trans_w_kernel<<<GRD(Lc * Ec * FFc), 256, 0, stream>>>(w1, w1T, Ec, FFc);
    trans_w_kernel<<<GRD(Lc * FFc * Ec), 256, 0, stream>>>(w2, w2T, FFc, Ec);

    embed_kernel<<<GRD(Mc * Ec), 256, 0, stream>>>(ctx, tok, pos, x);

    for (int l = 0; l < Lc; ++l) {
        for (int b0 = 0; b0 < Bc; b0 += CB) {
            int bcnt = (Bc - b0 < CB) ? (Bc - b0) : CB;
            int rows = bcnt * Tc;
            float* xc = x + (size_t)b0 * Tc * Ec;
            ln_kernel<<<rows / 4, 256, 0, stream>>>(
                xc, xn_c, ln1g + l * Ec, ln1b + l * Ec, rows);
            mfma_gemm<false, false, true><<<dim3(1152 / 128, rows / 128), 256, 0, stream>>>(
                xn_c, wqkvT + (size_t)l * 1152 * 384, nullptr, nullptr, qkv_c,
                1152, 384, 1152);
            attn_kernel<<<dim3(Tc / 64, Hc, bcnt), 256, 0, stream>>>(qkv_c, o_c);
            mfma_gemm<false, true, false><<<dim3(Ec / 128, rows / 128), 256, 0, stream>>>(
                o_c, wprojT + (size_t)l * 384 * 384, bproj + l * Ec, xc, xc,
                Ec, 384, Ec);
            ln_kernel<<<rows / 4, 256, 0, stream>>>(
                xc, xn_c, ln2g + l * Ec, ln2b + l * Ec, rows);
            mfma_gemm<true, false, true><<<dim3(FFc / 128, rows / 128), 256, 0, stream>>>(
                xn_c, w1T + (size_t)l * 1536 * 384, b1 + l * FFc, nullptr, ff_c,
                FFc, 384, FFc);
            mfma_gemm<false, true, false><<<dim3(Ec / 128, rows / 128), 256, 0, stream>>>(
                ff_c, w2T + (size_t)l * 384 * 1536, b2 + l * Ec, xc, xc,
                Ec, 1536, Ec);
        }
    }
    for (int b0 = 0; b0 < Bc; b0 += CB) {
        int bcnt = (Bc - b0 < CB) ? (Bc - b0) : CB;
        int rows = bcnt * Tc;
        float* xc = x + (size_t)b0 * Tc * Ec;
        ln_kernel<<<rows / 4, 256, 0, stream>>>(xc, xn_c, lnfg, lnfb, rows);
        head_kernel<<<GRD(rows * Vc), 256, 0, stream>>>(
            xn_c, whead, bhead, out + (size_t)b0 * Tc * Vc, rows);
    }
}

// Round 11
// 3218.790 us; speedup vs baseline: 7.5103x; 1.5111x over previous
//
#include <hip/hip_runtime.h>

// ---------------------------------------------------------------------------
// ROUND 11: MFMA flash attention (QK^T and PV on matrix cores) + r10 MFMA
// GEMMs. fp32 residual/output. B=128 T=256 E=384 H=6 HS=64 L=6 V=78 FF=1536.
// ---------------------------------------------------------------------------

#define Bc 128
#define Tc 256
#define Ec 384
#define Hc 6
#define HSc 64
#define Lc 6
#define Vc 78
#define FFc 1536
#define Mc (Bc * Tc)  // 32768 tokens

typedef unsigned short u16;
using bf16x8 = __attribute__((ext_vector_type(8))) short;
using f32x4 = __attribute__((ext_vector_type(4))) float;

__device__ __forceinline__ float b2f(u16 u) {
    union { float f; unsigned int i; } x;
    x.i = ((unsigned int)u) << 16;
    return x.f;
}
__device__ __forceinline__ u16 f2b(float f) {
    union { float f; unsigned int u; } x;
    x.f = f;
    unsigned int r = x.u + 0x7fffu + ((x.u >> 16) & 1u);  // RNE
    return (u16)(r >> 16);
}

__global__ __launch_bounds__(256) void poison_kernel(
    float* __restrict__ out, int n, float val) {
    int i = blockIdx.x * 256 + threadIdx.x;
    if (i < n) out[i] = val;
}

// --- weight pre-transpose to bf16 [N][K] ------------------------------------
__global__ __launch_bounds__(256) void trans_qkv_kernel(
    const float* __restrict__ in, u16* __restrict__ out) {
    int i = blockIdx.x * 256 + threadIdx.x;  // < L*H*E*192
    if (i >= Lc * Hc * Ec * 192) return;
    int f = i % 192;
    int r = i / 192;
    int e = r % Ec; r /= Ec;
    int h = r % Hc;
    int l = r / Hc;
    out[((size_t)l * 1152 + h * 192 + f) * Ec + e] = f2b(in[i]);
}
__global__ __launch_bounds__(256) void trans_w_kernel(
    const float* __restrict__ in, u16* __restrict__ out, int K, int N) {
    int i = blockIdx.x * 256 + threadIdx.x;  // < L*K*N
    if (i >= Lc * K * N) return;
    int n = i % N;
    int r = i / N;
    int k = r % K;
    int l = r / K;
    out[((size_t)l * N + n) * K + k] = f2b(in[i]);
}

// --- x[bt,e] = tok_emb[ctx[bt],e] + pos_emb[t,e]  (fp32) --------------------
__global__ __launch_bounds__(256) void embed_kernel(
    const int* __restrict__ ctx, const float* __restrict__ tok,
    const float* __restrict__ pos, float* __restrict__ x) {
    int i = blockIdx.x * 256 + threadIdx.x;
    if (i >= Mc * Ec) return;
    int e = i % Ec, bt = i / Ec, t = bt % Tc;
    x[i] = tok[ctx[bt] * Ec + e] + pos[t * Ec + e];
}

// --- layernorm fp32 in -> bf16 out: one wave per row ------------------------
__global__ __launch_bounds__(256) void ln_kernel(
    const float* __restrict__ X, u16* __restrict__ Y,
    const float* __restrict__ g, const float* __restrict__ b, int nrows) {
    int row = blockIdx.x * 4 + (threadIdx.x >> 6);
    int lane = threadIdx.x & 63;
    if (row >= nrows) return;
    const float* xr = X + (size_t)row * Ec;
    float v[6];
    float s = 0.f;
#pragma unroll
    for (int i = 0; i < 6; ++i) { v[i] = xr[lane + 64 * i]; s += v[i]; }
#pragma unroll
    for (int off = 32; off >= 1; off >>= 1) s += __shfl_xor(s, off, 64);
    float mean = s * (1.0f / Ec);
    float s2 = 0.f;
#pragma unroll
    for (int i = 0; i < 6; ++i) { float d = v[i] - mean; s2 += d * d; }
#pragma unroll
    for (int off = 32; off >= 1; off >>= 1) s2 += __shfl_xor(s2, off, 64);
    float rstd = rsqrtf(s2 * (1.0f / Ec) + 1e-5f);
    u16* yr = Y + (size_t)row * Ec;
#pragma unroll
    for (int i = 0; i < 6; ++i) {
        int e = lane + 64 * i;
        yr[e] = f2b((v[i] - mean) * rstd * g[e] + b[e]);
    }
}

// --- MFMA GEMM: C[*, ldC] = A[M,K](bf16) @ Wt[N,K]^T(bf16) [+bias][+R] ------
// 128x128 tile, BK=64, 4 waves (2x2 of 64x64). (layouts verified r10)
template <bool RELU, bool RESID, bool OUTBF16>
__global__ __launch_bounds__(256) void mfma_gemm(
    const u16* __restrict__ A, const u16* __restrict__ Wt,
    const float* __restrict__ bias, const float* R, void* C,
    int N, int K, int ldC) {
    __shared__ u16 As[128][80];
    __shared__ u16 Bs[128][80];
    int tid = threadIdx.x;
    int m0 = blockIdx.y * 128, n0 = blockIdx.x * 128;
    int w = tid >> 6, lane = tid & 63;
    int wm = (w >> 1) * 64, wn = (w & 1) * 64;
    int r16 = lane & 15, quad = lane >> 4;
    int sr = tid >> 3;
    int sk = (tid & 7) * 8;

    f32x4 acc[4][4] = {};

    for (int k0 = 0; k0 < K; k0 += 64) {
        __syncthreads();
#pragma unroll
        for (int j = 0; j < 4; ++j) {
            int r = sr + 32 * j;
            *reinterpret_cast<uint4*>(&As[r][sk]) =
                *reinterpret_cast<const uint4*>(&A[(size_t)(m0 + r) * K + k0 + sk]);
            *reinterpret_cast<uint4*>(&Bs[r][sk]) =
                *reinterpret_cast<const uint4*>(&Wt[(size_t)(n0 + r) * K + k0 + sk]);
        }
        __syncthreads();
#pragma unroll
        for (int kk = 0; kk < 2; ++kk) {
            bf16x8 af[4], bf[4];
#pragma unroll
            for (int i = 0; i < 4; ++i) {
                af[i] = *reinterpret_cast<const bf16x8*>(
                    &As[wm + i * 16 + r16][kk * 32 + quad * 8]);
                bf[i] = *reinterpret_cast<const bf16x8*>(
                    &Bs[wn + i * 16 + r16][kk * 32 + quad * 8]);
            }
#pragma unroll
            for (int mi = 0; mi < 4; ++mi)
#pragma unroll
                for (int ni = 0; ni < 4; ++ni)
                    acc[mi][ni] = __builtin_amdgcn_mfma_f32_16x16x32_bf16(
                        af[mi], bf[ni], acc[mi][ni], 0, 0, 0);
        }
    }

#pragma unroll
    for (int mi = 0; mi < 4; ++mi)
#pragma unroll
        for (int ni = 0; ni < 4; ++ni) {
            int gn = n0 + wn + ni * 16 + r16;
            float bv = bias ? bias[gn] : 0.f;
#pragma unroll
            for (int reg = 0; reg < 4; ++reg) {
                int gm = m0 + wm + mi * 16 + quad * 4 + reg;
                float v = acc[mi][ni][reg] + bv;
                if (RESID) v += R[(size_t)gm * ldC + gn];
                if (RELU) v = fmaxf(v, 0.f);
                if (OUTBF16)
                    ((u16*)C)[(size_t)gm * ldC + gn] = f2b(v);
                else
                    ((float*)C)[(size_t)gm * ldC + gn] = v;
            }
        }
}

// --- MFMA flash attention: block = (64-q tile, h, b); 4 waves x 16 rows -----
// qkv [bcnt*256,1152] bf16 chunk-local; o [bcnt*256,384] bf16 chunk-local.
// S = Q@K^T and O = P@V both use the r10-verified mfma operand layouts:
//   A[m=lane&15][k=quad*8+j] (row-major, K-contig); B-op[n=lane&15][k=...]
//   C/D[row=quad*4+reg][col=lane&15].
__global__ __launch_bounds__(256) void attn_kernel(
    const u16* __restrict__ qkv, u16* __restrict__ o) {
    __shared__ u16 Qs[64][72];
    __shared__ u16 Ks[64][72];
    __shared__ u16 Vt[64][72];      // V transposed: Vt[d][s]
    __shared__ u16 Ps[4][16][72];   // per-wave P tile (16 rows x 64 cols)
    int tid = threadIdx.x;
    int tt = blockIdx.x, h = blockIdx.y, b = blockIdx.z;
    int w = tid >> 6, lane = tid & 63;
    int r16 = lane & 15, quad = lane >> 4;
    int t0 = tt * 64;
    const u16* base = qkv + (size_t)b * Tc * 1152 + h * 192;

    int sr = tid >> 2, sd = (tid & 3) * 16;
    {   // stage Q (64 rows x 64 d, bf16)
        const u16* src = base + (size_t)(t0 + sr) * 1152 + sd;
        *reinterpret_cast<uint4*>(&Qs[sr][sd]) =
            *reinterpret_cast<const uint4*>(src);
        *reinterpret_cast<uint4*>(&Qs[sr][sd + 8]) =
            *reinterpret_cast<const uint4*>(src + 8);
    }

    float m_run[4], l_run[4];
#pragma unroll
    for (int r = 0; r < 4; ++r) { m_run[r] = -3.0e38f; l_run[r] = 0.f; }
    f32x4 acc_o[4] = {};  // [ni]: rows quad*4+reg, cols ni*16+r16

    for (int st = 0; st <= tt; ++st) {
        __syncthreads();
        {   // stage K[s][d] and Vt[d][s]
            const u16* ks = base + (size_t)(st * 64 + sr) * 1152 + 64 + sd;
            *reinterpret_cast<uint4*>(&Ks[sr][sd]) =
                *reinterpret_cast<const uint4*>(ks);
            *reinterpret_cast<uint4*>(&Ks[sr][sd + 8]) =
                *reinterpret_cast<const uint4*>(ks + 8);
            const u16* vs = base + (size_t)(st * 64 + sr) * 1152 + 128 + sd;
            u16 tv[16];
            *reinterpret_cast<uint4*>(tv) = *reinterpret_cast<const uint4*>(vs);
            *reinterpret_cast<uint4*>(tv + 8) =
                *reinterpret_cast<const uint4*>(vs + 8);
#pragma unroll
            for (int j = 0; j < 16; ++j) Vt[sd + j][sr] = tv[j];
        }
        __syncthreads();

        // ---- S = Q_w (16x64) @ K^T (64x64) ----
        f32x4 acc_s[4] = {};
        bf16x8 aq0 = *reinterpret_cast<const bf16x8*>(&Qs[w * 16 + r16][quad * 8]);
        bf16x8 aq1 = *reinterpret_cast<const bf16x8*>(&Qs[w * 16 + r16][32 + quad * 8]);
#pragma unroll
        for (int ni = 0; ni < 4; ++ni) {
            bf16x8 bk0 = *reinterpret_cast<const bf16x8*>(&Ks[ni * 16 + r16][quad * 8]);
            bf16x8 bk1 = *reinterpret_cast<const bf16x8*>(&Ks[ni * 16 + r16][32 + quad * 8]);
            acc_s[ni] = __builtin_amdgcn_mfma_f32_16x16x32_bf16(aq0, bk0, acc_s[ni], 0, 0, 0);
            acc_s[ni] = __builtin_amdgcn_mfma_f32_16x16x32_bf16(aq1, bk1, acc_s[ni], 0, 0, 0);
        }

        // ---- online softmax (rows = quad*4+reg; col-reduce over r16) ----
        float sc[4][4];
        float mt[4] = {-3.0e38f, -3.0e38f, -3.0e38f, -3.0e38f};
#pragma unroll
        for (int ni = 0; ni < 4; ++ni)
#pragma unroll
            for (int reg = 0; reg < 4; ++reg) {
                int col = st * 64 + ni * 16 + r16;
                int row = t0 + w * 16 + quad * 4 + reg;
                float v = (col <= row) ? acc_s[ni][reg] * 0.125f : -3.0e38f;
                sc[ni][reg] = v;
                mt[reg] = fmaxf(mt[reg], v);
            }
#pragma unroll
        for (int reg = 0; reg < 4; ++reg) {
#pragma unroll
            for (int off = 1; off <= 8; off <<= 1)
                mt[reg] = fmaxf(mt[reg], __shfl_xor(mt[reg], off, 64));
        }
        float alpha[4], lt[4];
#pragma unroll
        for (int reg = 0; reg < 4; ++reg) {
            float m_new = fmaxf(m_run[reg], mt[reg]);
            alpha[reg] = __expf(m_run[reg] - m_new);
            m_run[reg] = m_new;
            lt[reg] = 0.f;
        }
#pragma unroll
        for (int ni = 0; ni < 4; ++ni)
#pragma unroll
            for (int reg = 0; reg < 4; ++reg) {
                float p = __expf(sc[ni][reg] - m_run[reg]);
                lt[reg] += p;
                Ps[w][quad * 4 + reg][ni * 16 + r16] = f2b(p);
            }
#pragma unroll
        for (int reg = 0; reg < 4; ++reg) {
#pragma unroll
            for (int off = 1; off <= 8; off <<= 1)
                lt[reg] += __shfl_xor(lt[reg], off, 64);
            l_run[reg] = l_run[reg] * alpha[reg] + lt[reg];
        }
#pragma unroll
        for (int ni = 0; ni < 4; ++ni)
#pragma unroll
            for (int reg = 0; reg < 4; ++reg) acc_o[ni][reg] *= alpha[reg];
        __syncthreads();  // Ps write -> A-frag read (and pre-restage guard)

        // ---- O += P (16x64) @ V (64x64) via Vt ----
        bf16x8 ap0 = *reinterpret_cast<const bf16x8*>(&Ps[w][r16][quad * 8]);
        bf16x8 ap1 = *reinterpret_cast<const bf16x8*>(&Ps[w][r16][32 + quad * 8]);
#pragma unroll
        for (int ni = 0; ni < 4; ++ni) {
            bf16x8 bv0 = *reinterpret_cast<const bf16x8*>(&Vt[ni * 16 + r16][quad * 8]);
            bf16x8 bv1 = *reinterpret_cast<const bf16x8*>(&Vt[ni * 16 + r16][32 + quad * 8]);
            acc_o[ni] = __builtin_amdgcn_mfma_f32_16x16x32_bf16(ap0, bv0, acc_o[ni], 0, 0, 0);
            acc_o[ni] = __builtin_amdgcn_mfma_f32_16x16x32_bf16(ap1, bv1, acc_o[ni], 0, 0, 0);
        }
    }

    float inv[4];
#pragma unroll
    for (int reg = 0; reg < 4; ++reg) inv[reg] = 1.0f / l_run[reg];
#pragma unroll
    for (int ni = 0; ni < 4; ++ni)
#pragma unroll
        for (int reg = 0; reg < 4; ++reg) {
            int t = t0 + w * 16 + quad * 4 + reg;
            o[((size_t)b * Tc + t) * Ec + h * 64 + ni * 16 + r16] =
                f2b(acc_o[ni][reg] * inv[reg]);
        }
}

// --- head: out[m,v] = sum_e xn[m,e]*W[e,v] + bias[v]  (fp32 out) ------------
__global__ __launch_bounds__(256) void head_kernel(
    const u16* __restrict__ xn, const float* __restrict__ W,
    const float* __restrict__ bias, float* __restrict__ out, int rows) {
    int i = blockIdx.x * 256 + threadIdx.x;
    if (i >= rows * Vc) return;
    int m = i / Vc, v = i % Vc;
    const u16* xm = xn + (size_t)m * Ec;
    float acc = 0.f;
    for (int e = 0; e < Ec; ++e) acc += b2f(xm[e]) * W[(size_t)e * Vc + v];
    out[i] = acc + bias[v];
}

#define GRD(n) dim3(((n) + 255) / 256)

extern "C" void kernel_launch(void* const* d_in, const int* in_sizes, int n_in,
                              void* d_out, int out_size, void* d_ws, size_t ws_size,
                              hipStream_t stream) {
    const int* ctx = (const int*)d_in[0];
    const float* tok = (const float*)d_in[1];
    const float* pos = (const float*)d_in[2];
    const float* ln1g = (const float*)d_in[3];
    const float* ln1b = (const float*)d_in[4];
    const float* wqkv = (const float*)d_in[5];
    const float* wproj = (const float*)d_in[6];
    const float* bproj = (const float*)d_in[7];
    const float* ln2g = (const float*)d_in[8];
    const float* ln2b = (const float*)d_in[9];
    const float* w1 = (const float*)d_in[10];
    const float* b1 = (const float*)d_in[11];
    const float* w2 = (const float*)d_in[12];
    const float* b2 = (const float*)d_in[13];
    const float* lnfg = (const float*)d_in[14];
    const float* lnfb = (const float*)d_in[15];
    const float* whead = (const float*)d_in[16];
    const float* bhead = (const float*)d_in[17];
    float* out = (float*)d_out;

    // ---- workspace layout --------------------------------------------------
    char* ws = (char*)d_ws;
    float* x = (float*)ws;
    size_t off = (size_t)Mc * Ec * 4;                      // 50.3 MB
    u16* wqkvT = (u16*)(ws + off); off += (size_t)Lc * 1152 * 384 * 2;
    u16* wprojT = (u16*)(ws + off); off += (size_t)Lc * 384 * 384 * 2;
    u16* w1T = (u16*)(ws + off); off += (size_t)Lc * 1536 * 384 * 2;
    u16* w2T = (u16*)(ws + off); off += (size_t)Lc * 384 * 1536 * 2;
    const size_t per_b = (size_t)Tc * (Ec + 1152 + Ec + FFc) * 2;  // 1.77 MB
    if (ws_size < off + per_b) {
        poison_kernel<<<GRD(out_size), 256, 0, stream>>>(out, out_size, 200.0f);
        return;
    }
    int CB = (int)((ws_size - off) / per_b);
    if (CB > Bc) CB = Bc;
    u16* xn_c = (u16*)(ws + off);
    u16* qkv_c = xn_c + (size_t)CB * Tc * Ec;
    u16* o_c = qkv_c + (size_t)CB * Tc * 1152;
    u16* ff_c = o_c + (size_t)CB * Tc * Ec;

    // ---- weight transposes (bf16) -----------------------------------------
    trans_qkv_kernel<<<GRD(Lc * Hc * Ec * 192), 256, 0, stream>>>(wqkv, wqkvT);
    trans_w_kernel<<<GRD(Lc * Ec * Ec), 256, 0, stream>>>(wproj, wprojT, Ec, Ec);
    trans_w_kernel<<<GRD(Lc * Ec * FFc), 256, 0, stream>>>(w1, w1T, Ec, FFc);
    trans_w_kernel<<<GRD(Lc * FFc * Ec), 256, 0, stream>>>(w2, w2T, FFc, Ec);

    embed_kernel<<<GRD(Mc * Ec), 256, 0, stream>>>(ctx, tok, pos, x);

    for (int l = 0; l < Lc; ++l) {
        for (int b0 = 0; b0 < Bc; b0 += CB) {
            int bcnt = (Bc - b0 < CB) ? (Bc - b0) : CB;
            int rows = bcnt * Tc;
            float* xc = x + (size_t)b0 * Tc * Ec;
            ln_kernel<<<rows / 4, 256, 0, stream>>>(
                xc, xn_c, ln1g + l * Ec, ln1b + l * Ec, rows);
            mfma_gemm<false, false, true><<<dim3(1152 / 128, rows / 128), 256, 0, stream>>>(
                xn_c, wqkvT + (size_t)l * 1152 * 384, nullptr, nullptr, qkv_c,
                1152, 384, 1152);
            attn_kernel<<<dim3(Tc / 64, Hc, bcnt), 256, 0, stream>>>(qkv_c, o_c);
            mfma_gemm<false, true, false><<<dim3(Ec / 128, rows / 128), 256, 0, stream>>>(
                o_c, wprojT + (size_t)l * 384 * 384, bproj + l * Ec, xc, xc,
                Ec, 384, Ec);
            ln_kernel<<<rows / 4, 256, 0, stream>>>(
                xc, xn_c, ln2g + l * Ec, ln2b + l * Ec, rows);
            mfma_gemm<true, false, true><<<dim3(FFc / 128, rows / 128), 256, 0, stream>>>(
                xn_c, w1T + (size_t)l * 1536 * 384, b1 + l * FFc, nullptr, ff_c,
                FFc, 384, FFc);
            mfma_gemm<false, true, false><<<dim3(Ec / 128, rows / 128), 256, 0, stream>>>(
                ff_c, w2T + (size_t)l * 384 * 1536, b2 + l * Ec, xc, xc,
                Ec, 1536, Ec);
        }
    }
    for (int b0 = 0; b0 < Bc; b0 += CB) {
        int bcnt = (Bc - b0 < CB) ? (Bc - b0) : CB;
        int rows = bcnt * Tc;
        float* xc = x + (size_t)b0 * Tc * Ec;
        ln_kernel<<<rows / 4, 256, 0, stream>>>(xc, xn_c, lnfg, lnfb, rows);
        head_kernel<<<GRD(rows * Vc), 256, 0, stream>>>(
            xn_c, whead, bhead, out + (size_t)b0 * Tc * Vc, rows);
    }
}

// Round 12
// 3070.195 us; speedup vs baseline: 7.8738x; 1.0484x over previous
//
#include <hip/hip_runtime.h>

// ---------------------------------------------------------------------------
// ROUND 12: head via MFMA GEMM (padded N-tile) + r11 MFMA GEMMs/attention.
// fp32 residual/output. B=128 T=256 E=384 H=6 HS=64 L=6 V=78 FF=1536.
// ---------------------------------------------------------------------------

#define Bc 128
#define Tc 256
#define Ec 384
#define Hc 6
#define HSc 64
#define Lc 6
#define Vc 78
#define FFc 1536
#define Mc (Bc * Tc)  // 32768 tokens

typedef unsigned short u16;
using bf16x8 = __attribute__((ext_vector_type(8))) short;
using f32x4 = __attribute__((ext_vector_type(4))) float;

__device__ __forceinline__ float b2f(u16 u) {
    union { float f; unsigned int i; } x;
    x.i = ((unsigned int)u) << 16;
    return x.f;
}
__device__ __forceinline__ u16 f2b(float f) {
    union { float f; unsigned int u; } x;
    x.f = f;
    unsigned int r = x.u + 0x7fffu + ((x.u >> 16) & 1u);  // RNE
    return (u16)(r >> 16);
}

__global__ __launch_bounds__(256) void poison_kernel(
    float* __restrict__ out, int n, float val) {
    int i = blockIdx.x * 256 + threadIdx.x;
    if (i < n) out[i] = val;
}

// --- weight pre-transpose to bf16 [N][K] ------------------------------------
__global__ __launch_bounds__(256) void trans_qkv_kernel(
    const float* __restrict__ in, u16* __restrict__ out) {
    int i = blockIdx.x * 256 + threadIdx.x;  // < L*H*E*192
    if (i >= Lc * Hc * Ec * 192) return;
    int f = i % 192;
    int r = i / 192;
    int e = r % Ec; r /= Ec;
    int h = r % Hc;
    int l = r / Hc;
    out[((size_t)l * 1152 + h * 192 + f) * Ec + e] = f2b(in[i]);
}
__global__ __launch_bounds__(256) void trans_w_kernel(
    const float* __restrict__ in, u16* __restrict__ out, int K, int N) {
    int i = blockIdx.x * 256 + threadIdx.x;  // < L*K*N
    if (i >= Lc * K * N) return;
    int n = i % N;
    int r = i / N;
    int k = r % K;
    int l = r / K;
    out[((size_t)l * N + n) * K + k] = f2b(in[i]);
}
// head: in[e*Vc+v] -> out[v*Ec+e], v<Vc (rows Vc..127 pre-zeroed)
__global__ __launch_bounds__(256) void trans_head_kernel(
    const float* __restrict__ in, u16* __restrict__ out) {
    int i = blockIdx.x * 256 + threadIdx.x;  // < Ec*Vc
    if (i >= Ec * Vc) return;
    int v = i % Vc, e = i / Vc;
    out[(size_t)v * Ec + e] = f2b(in[i]);
}

// --- x[bt,e] = tok_emb[ctx[bt],e] + pos_emb[t,e]  (fp32) --------------------
__global__ __launch_bounds__(256) void embed_kernel(
    const int* __restrict__ ctx, const float* __restrict__ tok,
    const float* __restrict__ pos, float* __restrict__ x) {
    int i = blockIdx.x * 256 + threadIdx.x;
    if (i >= Mc * Ec) return;
    int e = i % Ec, bt = i / Ec, t = bt % Tc;
    x[i] = tok[ctx[bt] * Ec + e] + pos[t * Ec + e];
}

// --- layernorm fp32 in -> bf16 out: one wave per row ------------------------
__global__ __launch_bounds__(256) void ln_kernel(
    const float* __restrict__ X, u16* __restrict__ Y,
    const float* __restrict__ g, const float* __restrict__ b, int nrows) {
    int row = blockIdx.x * 4 + (threadIdx.x >> 6);
    int lane = threadIdx.x & 63;
    if (row >= nrows) return;
    const float* xr = X + (size_t)row * Ec;
    float v[6];
    float s = 0.f;
#pragma unroll
    for (int i = 0; i < 6; ++i) { v[i] = xr[lane + 64 * i]; s += v[i]; }
#pragma unroll
    for (int off = 32; off >= 1; off >>= 1) s += __shfl_xor(s, off, 64);
    float mean = s * (1.0f / Ec);
    float s2 = 0.f;
#pragma unroll
    for (int i = 0; i < 6; ++i) { float d = v[i] - mean; s2 += d * d; }
#pragma unroll
    for (int off = 32; off >= 1; off >>= 1) s2 += __shfl_xor(s2, off, 64);
    float rstd = rsqrtf(s2 * (1.0f / Ec) + 1e-5f);
    u16* yr = Y + (size_t)row * Ec;
#pragma unroll
    for (int i = 0; i < 6; ++i) {
        int e = lane + 64 * i;
        yr[e] = f2b((v[i] - mean) * rstd * g[e] + b[e]);
    }
}

// --- MFMA GEMM: C[*, ldC] = A[M,K](bf16) @ Wt[N,K]^T(bf16) [+bias][+R] ------
// 128x128 tile, BK=64, 4 waves (2x2 of 64x64). NV = valid N for store/bias
// guard (Wt must be padded to the 128-tile in N). (layouts verified r10)
template <bool RELU, bool RESID, bool OUTBF16>
__global__ __launch_bounds__(256) void mfma_gemm(
    const u16* __restrict__ A, const u16* __restrict__ Wt,
    const float* __restrict__ bias, const float* R, void* C,
    int K, int ldC, int NV) {
    __shared__ u16 As[128][80];
    __shared__ u16 Bs[128][80];
    int tid = threadIdx.x;
    int m0 = blockIdx.y * 128, n0 = blockIdx.x * 128;
    int w = tid >> 6, lane = tid & 63;
    int wm = (w >> 1) * 64, wn = (w & 1) * 64;
    int r16 = lane & 15, quad = lane >> 4;
    int sr = tid >> 3;
    int sk = (tid & 7) * 8;

    f32x4 acc[4][4] = {};

    for (int k0 = 0; k0 < K; k0 += 64) {
        __syncthreads();
#pragma unroll
        for (int j = 0; j < 4; ++j) {
            int r = sr + 32 * j;
            *reinterpret_cast<uint4*>(&As[r][sk]) =
                *reinterpret_cast<const uint4*>(&A[(size_t)(m0 + r) * K + k0 + sk]);
            *reinterpret_cast<uint4*>(&Bs[r][sk]) =
                *reinterpret_cast<const uint4*>(&Wt[(size_t)(n0 + r) * K + k0 + sk]);
        }
        __syncthreads();
#pragma unroll
        for (int kk = 0; kk < 2; ++kk) {
            bf16x8 af[4], bf[4];
#pragma unroll
            for (int i = 0; i < 4; ++i) {
                af[i] = *reinterpret_cast<const bf16x8*>(
                    &As[wm + i * 16 + r16][kk * 32 + quad * 8]);
                bf[i] = *reinterpret_cast<const bf16x8*>(
                    &Bs[wn + i * 16 + r16][kk * 32 + quad * 8]);
            }
#pragma unroll
            for (int mi = 0; mi < 4; ++mi)
#pragma unroll
                for (int ni = 0; ni < 4; ++ni)
                    acc[mi][ni] = __builtin_amdgcn_mfma_f32_16x16x32_bf16(
                        af[mi], bf[ni], acc[mi][ni], 0, 0, 0);
        }
    }

#pragma unroll
    for (int mi = 0; mi < 4; ++mi)
#pragma unroll
        for (int ni = 0; ni < 4; ++ni) {
            int gn = n0 + wn + ni * 16 + r16;
            if (gn >= NV) continue;
            float bv = bias ? bias[gn] : 0.f;
#pragma unroll
            for (int reg = 0; reg < 4; ++reg) {
                int gm = m0 + wm + mi * 16 + quad * 4 + reg;
                float v = acc[mi][ni][reg] + bv;
                if (RESID) v += R[(size_t)gm * ldC + gn];
                if (RELU) v = fmaxf(v, 0.f);
                if (OUTBF16)
                    ((u16*)C)[(size_t)gm * ldC + gn] = f2b(v);
                else
                    ((float*)C)[(size_t)gm * ldC + gn] = v;
            }
        }
}

// --- MFMA flash attention (r11-verified) ------------------------------------
__global__ __launch_bounds__(256) void attn_kernel(
    const u16* __restrict__ qkv, u16* __restrict__ o) {
    __shared__ u16 Qs[64][72];
    __shared__ u16 Ks[64][72];
    __shared__ u16 Vt[64][72];
    __shared__ u16 Ps[4][16][72];
    int tid = threadIdx.x;
    int tt = blockIdx.x, h = blockIdx.y, b = blockIdx.z;
    int w = tid >> 6, lane = tid & 63;
    int r16 = lane & 15, quad = lane >> 4;
    int t0 = tt * 64;
    const u16* base = qkv + (size_t)b * Tc * 1152 + h * 192;

    int sr = tid >> 2, sd = (tid & 3) * 16;
    {
        const u16* src = base + (size_t)(t0 + sr) * 1152 + sd;
        *reinterpret_cast<uint4*>(&Qs[sr][sd]) =
            *reinterpret_cast<const uint4*>(src);
        *reinterpret_cast<uint4*>(&Qs[sr][sd + 8]) =
            *reinterpret_cast<const uint4*>(src + 8);
    }

    float m_run[4], l_run[4];
#pragma unroll
    for (int r = 0; r < 4; ++r) { m_run[r] = -3.0e38f; l_run[r] = 0.f; }
    f32x4 acc_o[4] = {};

    for (int st = 0; st <= tt; ++st) {
        __syncthreads();
        {
            const u16* ks = base + (size_t)(st * 64 + sr) * 1152 + 64 + sd;
            *reinterpret_cast<uint4*>(&Ks[sr][sd]) =
                *reinterpret_cast<const uint4*>(ks);
            *reinterpret_cast<uint4*>(&Ks[sr][sd + 8]) =
                *reinterpret_cast<const uint4*>(ks + 8);
            const u16* vs = base + (size_t)(st * 64 + sr) * 1152 + 128 + sd;
            u16 tv[16];
            *reinterpret_cast<uint4*>(tv) = *reinterpret_cast<const uint4*>(vs);
            *reinterpret_cast<uint4*>(tv + 8) =
                *reinterpret_cast<const uint4*>(vs + 8);
#pragma unroll
            for (int j = 0; j < 16; ++j) Vt[sd + j][sr] = tv[j];
        }
        __syncthreads();

        f32x4 acc_s[4] = {};
        bf16x8 aq0 = *reinterpret_cast<const bf16x8*>(&Qs[w * 16 + r16][quad * 8]);
        bf16x8 aq1 = *reinterpret_cast<const bf16x8*>(&Qs[w * 16 + r16][32 + quad * 8]);
#pragma unroll
        for (int ni = 0; ni < 4; ++ni) {
            bf16x8 bk0 = *reinterpret_cast<const bf16x8*>(&Ks[ni * 16 + r16][quad * 8]);
            bf16x8 bk1 = *reinterpret_cast<const bf16x8*>(&Ks[ni * 16 + r16][32 + quad * 8]);
            acc_s[ni] = __builtin_amdgcn_mfma_f32_16x16x32_bf16(aq0, bk0, acc_s[ni], 0, 0, 0);
            acc_s[ni] = __builtin_amdgcn_mfma_f32_16x16x32_bf16(aq1, bk1, acc_s[ni], 0, 0, 0);
        }

        float sc[4][4];
        float mt[4] = {-3.0e38f, -3.0e38f, -3.0e38f, -3.0e38f};
#pragma unroll
        for (int ni = 0; ni < 4; ++ni)
#pragma unroll
            for (int reg = 0; reg < 4; ++reg) {
                int col = st * 64 + ni * 16 + r16;
                int row = t0 + w * 16 + quad * 4 + reg;
                float v = (col <= row) ? acc_s[ni][reg] * 0.125f : -3.0e38f;
                sc[ni][reg] = v;
                mt[reg] = fmaxf(mt[reg], v);
            }
#pragma unroll
        for (int reg = 0; reg < 4; ++reg) {
#pragma unroll
            for (int off = 1; off <= 8; off <<= 1)
                mt[reg] = fmaxf(mt[reg], __shfl_xor(mt[reg], off, 64));
        }
        float alpha[4], lt[4];
#pragma unroll
        for (int reg = 0; reg < 4; ++reg) {
            float m_new = fmaxf(m_run[reg], mt[reg]);
            alpha[reg] = __expf(m_run[reg] - m_new);
            m_run[reg] = m_new;
            lt[reg] = 0.f;
        }
#pragma unroll
        for (int ni = 0; ni < 4; ++ni)
#pragma unroll
            for (int reg = 0; reg < 4; ++reg) {
                float p = __expf(sc[ni][reg] - m_run[reg]);
                lt[reg] += p;
                Ps[w][quad * 4 + reg][ni * 16 + r16] = f2b(p);
            }
#pragma unroll
        for (int reg = 0; reg < 4; ++reg) {
#pragma unroll
            for (int off = 1; off <= 8; off <<= 1)
                lt[reg] += __shfl_xor(lt[reg], off, 64);
            l_run[reg] = l_run[reg] * alpha[reg] + lt[reg];
        }
#pragma unroll
        for (int ni = 0; ni < 4; ++ni)
#pragma unroll
            for (int reg = 0; reg < 4; ++reg) acc_o[ni][reg] *= alpha[reg];
        __syncthreads();

        bf16x8 ap0 = *reinterpret_cast<const bf16x8*>(&Ps[w][r16][quad * 8]);
        bf16x8 ap1 = *reinterpret_cast<const bf16x8*>(&Ps[w][r16][32 + quad * 8]);
#pragma unroll
        for (int ni = 0; ni < 4; ++ni) {
            bf16x8 bv0 = *reinterpret_cast<const bf16x8*>(&Vt[ni * 16 + r16][quad * 8]);
            bf16x8 bv1 = *reinterpret_cast<const bf16x8*>(&Vt[ni * 16 + r16][32 + quad * 8]);
            acc_o[ni] = __builtin_amdgcn_mfma_f32_16x16x32_bf16(ap0, bv0, acc_o[ni], 0, 0, 0);
            acc_o[ni] = __builtin_amdgcn_mfma_f32_16x16x32_bf16(ap1, bv1, acc_o[ni], 0, 0, 0);
        }
    }

    float inv[4];
#pragma unroll
    for (int reg = 0; reg < 4; ++reg) inv[reg] = 1.0f / l_run[reg];
#pragma unroll
    for (int ni = 0; ni < 4; ++ni)
#pragma unroll
        for (int reg = 0; reg < 4; ++reg) {
            int t = t0 + w * 16 + quad * 4 + reg;
            o[((size_t)b * Tc + t) * Ec + h * 64 + ni * 16 + r16] =
                f2b(acc_o[ni][reg] * inv[reg]);
        }
}

#define GRD(n) dim3(((n) + 255) / 256)

extern "C" void kernel_launch(void* const* d_in, const int* in_sizes, int n_in,
                              void* d_out, int out_size, void* d_ws, size_t ws_size,
                              hipStream_t stream) {
    const int* ctx = (const int*)d_in[0];
    const float* tok = (const float*)d_in[1];
    const float* pos = (const float*)d_in[2];
    const float* ln1g = (const float*)d_in[3];
    const float* ln1b = (const float*)d_in[4];
    const float* wqkv = (const float*)d_in[5];
    const float* wproj = (const float*)d_in[6];
    const float* bproj = (const float*)d_in[7];
    const float* ln2g = (const float*)d_in[8];
    const float* ln2b = (const float*)d_in[9];
    const float* w1 = (const float*)d_in[10];
    const float* b1 = (const float*)d_in[11];
    const float* w2 = (const float*)d_in[12];
    const float* b2 = (const float*)d_in[13];
    const float* lnfg = (const float*)d_in[14];
    const float* lnfb = (const float*)d_in[15];
    const float* whead = (const float*)d_in[16];
    const float* bhead = (const float*)d_in[17];
    float* out = (float*)d_out;

    // ---- workspace layout --------------------------------------------------
    char* ws = (char*)d_ws;
    float* x = (float*)ws;
    size_t off = (size_t)Mc * Ec * 4;                      // 50.3 MB
    u16* wqkvT = (u16*)(ws + off); off += (size_t)Lc * 1152 * 384 * 2;
    u16* wprojT = (u16*)(ws + off); off += (size_t)Lc * 384 * 384 * 2;
    u16* w1T = (u16*)(ws + off); off += (size_t)Lc * 1536 * 384 * 2;
    u16* w2T = (u16*)(ws + off); off += (size_t)Lc * 384 * 1536 * 2;
    u16* wheadT = (u16*)(ws + off); off += (size_t)128 * 384 * 2;  // padded
    const size_t per_b = (size_t)Tc * (Ec + 1152 + Ec + FFc) * 2;  // 1.77 MB
    if (ws_size < off + per_b) {
        poison_kernel<<<GRD(out_size), 256, 0, stream>>>(out, out_size, 200.0f);
        return;
    }
    int CB = (int)((ws_size - off) / per_b);
    if (CB > Bc) CB = Bc;
    u16* xn_c = (u16*)(ws + off);
    u16* qkv_c = xn_c + (size_t)CB * Tc * Ec;
    u16* o_c = qkv_c + (size_t)CB * Tc * 1152;
    u16* ff_c = o_c + (size_t)CB * Tc * Ec;

    // ---- weight transposes (bf16) -----------------------------------------
    trans_qkv_kernel<<<GRD(Lc * Hc * Ec * 192), 256, 0, stream>>>(wqkv, wqkvT);
    trans_w_kernel<<<GRD(Lc * Ec * Ec), 256, 0, stream>>>(wproj, wprojT, Ec, Ec);
    trans_w_kernel<<<GRD(Lc * Ec * FFc), 256, 0, stream>>>(w1, w1T, Ec, FFc);
    trans_w_kernel<<<GRD(Lc * FFc * Ec), 256, 0, stream>>>(w2, w2T, FFc, Ec);
    hipMemsetAsync(wheadT, 0, (size_t)128 * 384 * 2, stream);
    trans_head_kernel<<<GRD(Ec * Vc), 256, 0, stream>>>(whead, wheadT);

    embed_kernel<<<GRD(Mc * Ec), 256, 0, stream>>>(ctx, tok, pos, x);

    for (int l = 0; l < Lc; ++l) {
        for (int b0 = 0; b0 < Bc; b0 += CB) {
            int bcnt = (Bc - b0 < CB) ? (Bc - b0) : CB;
            int rows = bcnt * Tc;
            float* xc = x + (size_t)b0 * Tc * Ec;
            ln_kernel<<<rows / 4, 256, 0, stream>>>(
                xc, xn_c, ln1g + l * Ec, ln1b + l * Ec, rows);
            mfma_gemm<false, false, true><<<dim3(1152 / 128, rows / 128), 256, 0, stream>>>(
                xn_c, wqkvT + (size_t)l * 1152 * 384, nullptr, nullptr, qkv_c,
                384, 1152, 1152);
            attn_kernel<<<dim3(Tc / 64, Hc, bcnt), 256, 0, stream>>>(qkv_c, o_c);
            mfma_gemm<false, true, false><<<dim3(Ec / 128, rows / 128), 256, 0, stream>>>(
                o_c, wprojT + (size_t)l * 384 * 384, bproj + l * Ec, xc, xc,
                384, Ec, Ec);
            ln_kernel<<<rows / 4, 256, 0, stream>>>(
                xc, xn_c, ln2g + l * Ec, ln2b + l * Ec, rows);
            mfma_gemm<true, false, true><<<dim3(FFc / 128, rows / 128), 256, 0, stream>>>(
                xn_c, w1T + (size_t)l * 1536 * 384, b1 + l * FFc, nullptr, ff_c,
                384, FFc, FFc);
            mfma_gemm<false, true, false><<<dim3(Ec / 128, rows / 128), 256, 0, stream>>>(
                ff_c, w2T + (size_t)l * 384 * 1536, b2 + l * Ec, xc, xc,
                1536, Ec, Ec);
        }
    }
    for (int b0 = 0; b0 < Bc; b0 += CB) {
        int bcnt = (Bc - b0 < CB) ? (Bc - b0) : CB;
        int rows = bcnt * Tc;
        float* xc = x + (size_t)b0 * Tc * Ec;
        ln_kernel<<<rows / 4, 256, 0, stream>>>(xc, xn_c, lnfg, lnfb, rows);
        mfma_gemm<false, false, false><<<dim3(1, rows / 128), 256, 0, stream>>>(
            xn_c, wheadT, bhead, nullptr, out + (size_t)b0 * Tc * Vc,
            384, Vc, Vc);
    }
}